// Round 5
// baseline (2093.407 us; speedup 1.0000x reference)
//
#include <hip/hip_runtime.h>
#include <hip/hip_bf16.h>
#include <cstddef>

#define HIDDEN 512
#define ATOM_FDIM 133
#define BOND_FDIM 14
#define FB_DIM 147
#define MAX_NB 6
#define BM 64
#define AROW 40            // A LDS row pitch in ushorts (80 B)
#define NT_MSG 16          // K-tiles for message phase (512/32)
#define NT_ATOM 5          // K-tiles for atom phase (160/32, pad of 133)

typedef __attribute__((ext_vector_type(8))) short s16x8;
typedef __attribute__((ext_vector_type(4))) short s16x4;
typedef __attribute__((ext_vector_type(4))) float f32x4;

__device__ __forceinline__ float uf(unsigned short u) {
    return __uint_as_float(((unsigned)u) << 16);
}
__device__ __forceinline__ unsigned short fb(float f) {
    __hip_bfloat16 h = __float2bfloat16(f);
    return *reinterpret_cast<unsigned short*>(&h);
}

// ---------------------------------------------------------------------------
// One-time weight convert: f32 [Ksrc][512] -> bf16 MFMA-fragment order.
// Chunk c (16 B = 8 bf16): tile=c>>11, n=(c&2047)>>2, s=c&3 holds
// W[tile*32 + s*8 + e][n].  A lane reads its B-fragment (col n, k-octet lhi)
// directly from global: chunk tile*2048 + n*4 + lhi.  A wave's 8 fragment
// loads each cover a contiguous 1 KB region (16 cols x 64 B) -> coalesced.
// ---------------------------------------------------------------------------
__global__ __launch_bounds__(256) void cvt_w(const float* __restrict__ src,
                                             unsigned short* __restrict__ dst,
                                             int Ksrc, int nchunks)
{
    int c = blockIdx.x * 256 + threadIdx.x;
    if (c >= nchunks) return;
    int tile = c >> 11, pc = c & 2047, n = pc >> 2, s = pc & 3;
    s16x8 o;
    #pragma unroll
    for (int e = 0; e < 8; e++) {
        int k = tile * 32 + s * 8 + e;
        float v = (k < Ksrc) ? src[(size_t)k * HIDDEN + n] : 0.f;
        o[e] = (short)fb(v);
    }
    reinterpret_cast<s16x8*>(dst)[c] = o;
}

// ---------------------------------------------------------------------------
// MFMA multi-phase GEMM. 512 thr = 8 waves (2M x 4N), BM=64 x BN=512, BK=32.
// Wave (wm,wn) owns rows [wm*32,+32) x cols [wn*128,+128): 2x8 frags, acc=64.
// B fragments load DIRECTLY from global (L2-hot, fragment-ordered tiles).
// A (gather-sum) staged in double-buffered LDS; raw s_barrier + lgkmcnt-only
// waits so gather loads (issued 2 tiles ahead) stay in flight across
// barriers (vmcnt never force-drained in the loop).
// ---------------------------------------------------------------------------
template<int EPI, bool P0, bool P1, bool P2>
__global__ __launch_bounds__(512, 3) void mfma_gemm(
    const unsigned short* __restrict__ msg, const int* __restrict__ a2a,
    const unsigned short* __restrict__ Wm,
    const float* __restrict__ atomf, const unsigned short* __restrict__ Wa,
    const float* __restrict__ fbonds, const int* __restrict__ a2b,
    const unsigned short* __restrict__ Wb,
    const unsigned short* __restrict__ base, const float* __restrict__ bias,
    unsigned short* __restrict__ outv, unsigned short* __restrict__ baseOut,
    int M)
{
    __shared__ unsigned short As[2][BM * AROW];      // 10 KB total

    const int t    = threadIdx.x;
    const int m0   = blockIdx.x * BM;
    const int lane = t & 63;
    const int l15  = lane & 15, lhi = lane >> 4;
    const int w    = t >> 6, wm = w >> 2, wn = w & 3;
    const int rs   = t >> 3, o8 = t & 7;             // staging: row, 8B-octet

    int srow = m0 + rs; if (srow >= M) srow = M - 1;

    f32x4 acc[2][8];
    #pragma unroll
    for (int mr = 0; mr < 2; mr++)
        #pragma unroll
        for (int nr = 0; nr < 8; nr++)
            acc[mr][nr] = (f32x4){0.f, 0.f, 0.f, 0.f};

    auto compute = [&](int buf, const unsigned short* __restrict__ Wt, int tile) {
        s16x8 af[2];
        #pragma unroll
        for (int mr = 0; mr < 2; mr++)
            af[mr] = *reinterpret_cast<const s16x8*>(
                &As[buf][(wm * 32 + mr * 16 + l15) * AROW + lhi * 8]);
        const unsigned short* bb =
            Wt + (size_t)tile * (HIDDEN * 32) + (size_t)(wn * 128 + l15) * 32 + lhi * 8;
        #pragma unroll
        for (int nr = 0; nr < 8; nr++) {
            s16x8 bf = *reinterpret_cast<const s16x8*>(bb + nr * 512);
            #pragma unroll
            for (int mr = 0; mr < 2; mr++)
                acc[mr][nr] = __builtin_amdgcn_mfma_f32_16x16x32_bf16(af[mr], bf, acc[mr][nr], 0, 0, 0);
        }
    };

    // ---- P0: gathered message, K = 512, 2-deep pipelined ----
    if (P0) {
        const unsigned short* pA[MAX_NB];
        #pragma unroll
        for (int j = 0; j < MAX_NB; j++)
            pA[j] = msg + (size_t)a2a[(size_t)srow * MAX_NB + j] * HIDDEN + o8 * 4;

        s16x4 pre0[MAX_NB], pre1[MAX_NB];
        auto issue = [&](s16x4* pre, int tile) {
            #pragma unroll
            for (int j = 0; j < MAX_NB; j++)
                pre[j] = *reinterpret_cast<const s16x4*>(pA[j] + tile * 32);
        };
        auto writeA = [&](int buf, s16x4* pre) {
            float s0 = 0.f, s1 = 0.f, s2 = 0.f, s3 = 0.f;
            #pragma unroll
            for (int j = 0; j < MAX_NB; j++) {
                s0 += uf((unsigned short)pre[j][0]);
                s1 += uf((unsigned short)pre[j][1]);
                s2 += uf((unsigned short)pre[j][2]);
                s3 += uf((unsigned short)pre[j][3]);
            }
            s16x4 o;
            o[0] = (short)fb(s0); o[1] = (short)fb(s1);
            o[2] = (short)fb(s2); o[3] = (short)fb(s3);
            *reinterpret_cast<s16x4*>(&As[buf][rs * AROW + o8 * 4]) = o;
        };

        issue(pre0, 0);
        issue(pre1, 1);
        writeA(0, pre0);
        asm volatile("s_waitcnt lgkmcnt(0)" ::: "memory");
        __builtin_amdgcn_s_barrier();
        #pragma unroll
        for (int tile = 0; tile < NT_MSG; ++tile) {
            s16x4* slotCur = (tile & 1) ? pre1 : pre0;   // freed last iter
            s16x4* slotNxt = (tile & 1) ? pre0 : pre1;   // holds gather(tile+1)
            if (tile + 2 < NT_MSG) issue(slotCur, tile + 2);
            __builtin_amdgcn_sched_barrier(0);
            compute(tile & 1, Wm, tile);
            if (tile + 1 < NT_MSG) {
                writeA((tile + 1) & 1, slotNxt);
                asm volatile("s_waitcnt lgkmcnt(0)" ::: "memory");
                __builtin_amdgcn_s_barrier();
            }
        }
    }
    // ---- P1: direct atom features, K = 160 (pad of 133) ----
    if (P1) {
        #pragma unroll
        for (int tile = 0; tile < NT_ATOM; ++tile) {
            int buf = tile & 1;
            float v[4];
            #pragma unroll
            for (int e = 0; e < 4; e++) {
                int k = tile * 32 + o8 * 4 + e;
                v[e] = (k < ATOM_FDIM && (m0 + rs) < M)
                           ? atomf[(size_t)(m0 + rs) * ATOM_FDIM + k] : 0.f;
            }
            s16x4 o;
            #pragma unroll
            for (int e = 0; e < 4; e++) o[e] = (short)fb(v[e]);
            *reinterpret_cast<s16x4*>(&As[buf][rs * AROW + o8 * 4]) = o;
            asm volatile("s_waitcnt lgkmcnt(0)" ::: "memory");
            __builtin_amdgcn_s_barrier();
            compute(buf, Wa, tile);
        }
    }
    // ---- P2: gathered bond features, K = 32 (pad of 14) ----
    if (P2) {
        float s[4] = {0.f, 0.f, 0.f, 0.f};
        #pragma unroll
        for (int j = 0; j < MAX_NB; j++) {
            int b = a2b[(size_t)srow * MAX_NB + j];
            #pragma unroll
            for (int e = 0; e < 4; e++) {
                int k = o8 * 4 + e;
                if (k < BOND_FDIM) s[e] += fbonds[(size_t)b * FB_DIM + ATOM_FDIM + k];
            }
        }
        s16x4 o;
        #pragma unroll
        for (int e = 0; e < 4; e++) o[e] = (short)fb(s[e]);
        *reinterpret_cast<s16x4*>(&As[1][rs * AROW + o8 * 4]) = o;
        asm volatile("s_waitcnt lgkmcnt(0)" ::: "memory");
        __builtin_amdgcn_s_barrier();
        compute(1, Wb, 0);
    }

    // ---- epilogue ----
    #pragma unroll
    for (int mr = 0; mr < 2; mr++) {
        #pragma unroll
        for (int nr = 0; nr < 8; nr++) {
            int col = wn * 128 + nr * 16 + l15;
            #pragma unroll
            for (int rg = 0; rg < 4; rg++) {
                int row = m0 + wm * 32 + mr * 16 + lhi * 4 + rg;
                if (row >= M) continue;
                size_t idx = (size_t)row * HIDDEN + col;
                float v = acc[mr][nr][rg];
                if (EPI == 0) {
                    outv[idx] = fb(fmaxf(v, 0.f));
                    if (baseOut) baseOut[idx] = fb(v + uf(baseOut[idx]));
                } else if (EPI == 1) {
                    outv[idx] = fb(fmaxf(v + uf(base[idx]), 0.f));
                } else {
                    outv[idx] = fb(fmaxf(v + bias[col], 0.f));
                }
            }
        }
    }
}

// ---------------------------------------------------------------------------
// flags[i] = (sum of atom_features row i) > 0.  One wave per row.
// ---------------------------------------------------------------------------
__global__ __launch_bounds__(256) void flags_k(const float* __restrict__ af,
                                               float* __restrict__ flags, int M)
{
    int w    = (blockIdx.x * 256 + threadIdx.x) >> 6;
    int lane = threadIdx.x & 63;
    if (w >= M) return;
    const float* row = af + (size_t)w * ATOM_FDIM;
    float s = 0.f;
    for (int c = lane; c < ATOM_FDIM; c += 64) s += row[c];
    #pragma unroll
    for (int off = 32; off; off >>= 1) s += __shfl_down(s, off);
    if (lane == 0) flags[w] = (s > 0.f) ? 1.f : 0.f;
}

// ---------------------------------------------------------------------------
// c_b[i] = (sum_j f_bonds[a2b[i][j]][133:147]) @ W_h[512:526] -> bf16
// ---------------------------------------------------------------------------
__global__ __launch_bounds__(256) void cb_k(const float* __restrict__ f_bonds,
                                            const int*   __restrict__ a2b,
                                            const float* __restrict__ Wh2,
                                            unsigned short* __restrict__ cb, int M)
{
    int atom = blockIdx.x * 4 + (threadIdx.x >> 6);
    int lane = threadIdx.x & 63;
    if (atom >= M) return;
    int bidx = (lane < MAX_NB) ? a2b[(size_t)atom * MAX_NB + lane] : 0;
    float nb = 0.f;
    if (lane < BOND_FDIM) {
        #pragma unroll
        for (int j = 0; j < MAX_NB; j++) {
            int b = __shfl(bidx, j);
            nb += f_bonds[(size_t)b * FB_DIM + ATOM_FDIM + lane];
        }
    }
    float acc[8];
    #pragma unroll
    for (int ci = 0; ci < 8; ci++) acc[ci] = 0.f;
    #pragma unroll
    for (int k = 0; k < BOND_FDIM; k++) {
        float nbk = __shfl(nb, k);
        #pragma unroll
        for (int ci = 0; ci < 8; ci++)
            acc[ci] += nbk * Wh2[(size_t)k * HIDDEN + lane + (ci << 6)];
    }
    size_t rb = (size_t)atom * HIDDEN;
    #pragma unroll
    for (int ci = 0; ci < 8; ci++) cb[rb + lane + (ci << 6)] = fb(acc[ci]);
}

// ---------------------------------------------------------------------------
// Per-molecule segment mean + counts; mol_ids sorted -> binary search bounds.
// ---------------------------------------------------------------------------
__global__ __launch_bounds__(512) void seg_k(const unsigned short* __restrict__ hid,
                                             const float* __restrict__ flags,
                                             const int*   __restrict__ mol_ids,
                                             float* __restrict__ out, int M, int NM)
{
    int m = blockIdx.x;
    int t = threadIdx.x;
    int lo = 0, hi = M;
    while (lo < hi) { int mid = (lo + hi) >> 1; if (mol_ids[mid] < m) lo = mid + 1; else hi = mid; }
    int s = lo;
    lo = 0; hi = M;
    while (lo < hi) { int mid = (lo + hi) >> 1; if (mol_ids[mid] < m + 1) lo = mid + 1; else hi = mid; }
    int e = lo;

    float acc = 0.f;
    for (int a = s; a < e; a++) acc += uf(hid[(size_t)a * HIDDEN + t]);
    float nzp = 0.f;
    for (int a = s + t; a < e; a += 512) nzp += flags[a];
    __shared__ float red[512];
    red[t] = nzp; __syncthreads();
    for (int off = 256; off; off >>= 1) { if (t < off) red[t] += red[t + off]; __syncthreads(); }

    int cnt = e - s;
    float inv = 1.f / fmaxf((float)cnt, 1.f);
    out[(size_t)m * HIDDEN + t] = acc * inv;
    if (t == 0) {
        out[(size_t)NM * HIDDEN + 2 * m]     = red[0];
        out[(size_t)NM * HIDDEN + 2 * m + 1] = (float)cnt;
    }
}

// ---------------------------------------------------------------------------
extern "C" void kernel_launch(void* const* d_in, const int* in_sizes, int n_in,
                              void* d_out, int out_size, void* d_ws, size_t ws_size,
                              hipStream_t stream)
{
    const float* atomf   = (const float*)d_in[0];
    const float* f_bonds = (const float*)d_in[1];
    const int*   a2a     = (const int*)d_in[2];
    const int*   a2b     = (const int*)d_in[3];
    const int*   mol_ids = (const int*)d_in[4];
    const float* W_i     = (const float*)d_in[5];
    const float* W_h     = (const float*)d_in[6];
    const float* W_o     = (const float*)d_in[7];
    const float* b_o     = (const float*)d_in[8];
    float* out = (float*)d_out;

    const int M  = in_sizes[2] / MAX_NB;   // 100000
    const int NM = 1000;
    const size_t SZ  = (size_t)M * HIDDEN;
    const size_t SZb = SZ * sizeof(unsigned short);

    const float* Wh2f = W_h + (size_t)HIDDEN * HIDDEN;

    // ---- workspace layout ----
    const size_t TCH = HIDDEN * 32;             // ushorts per tile (16384)
    unsigned short* WiT  = (unsigned short*)d_ws;
    unsigned short* Wh1T = WiT  + 5  * TCH;
    unsigned short* Wh2T = Wh1T + 16 * TCH;
    unsigned short* Wo1T = Wh2T + 1  * TCH;
    unsigned short* Wo2T = Wo1T + 5  * TCH;
    unsigned short* wend = Wo2T + 16 * TCH;     // 43 tiles total
    float* flags = (float*)wend;
    char* p = (char*)(flags + M);
    const size_t fixed = (size_t)((char*)p - (char*)d_ws);

    const bool path3 = (ws_size >= fixed + 3 * SZb);
    unsigned short* baseB = nullptr;
    unsigned short *msgA, *msgB;
    if (path3) {
        baseB = (unsigned short*)p; p += SZb;
        msgA  = (unsigned short*)p; p += SZb;
        msgB  = (unsigned short*)p;
    } else {
        msgA  = (unsigned short*)p; p += SZb;
        msgB  = (unsigned short*)p;
    }

    const int gA = (M + 3) / 4;
    const int gG = (M + BM - 1) / BM;

    // ---- weight conversion (fragment-ordered bf16 tiles) ----
    cvt_w<<<(5  * 2048 + 255) / 256, 256, 0, stream>>>(W_i,  WiT,  ATOM_FDIM, 5  * 2048);
    cvt_w<<<(16 * 2048 + 255) / 256, 256, 0, stream>>>(W_h,  Wh1T, HIDDEN,    16 * 2048);
    cvt_w<<<(1  * 2048 + 255) / 256, 256, 0, stream>>>(Wh2f, Wh2T, BOND_FDIM, 1  * 2048);
    cvt_w<<<(5  * 2048 + 255) / 256, 256, 0, stream>>>(W_o,  Wo1T, ATOM_FDIM, 5  * 2048);
    cvt_w<<<(16 * 2048 + 255) / 256, 256, 0, stream>>>(W_o + (size_t)ATOM_FDIM * HIDDEN,
                                                       Wo2T, HIDDEN, 16 * 2048);
    flags_k<<<gA, 256, 0, stream>>>(atomf, flags, M);

    if (path3) {
        cb_k<<<gA, 256, 0, stream>>>(f_bonds, a2b, Wh2f, baseB, M);
        // msgA = relu(inp); baseB += inp
        mfma_gemm<0, false, true, false><<<gG, 512, 0, stream>>>(
            nullptr, nullptr, nullptr, atomf, WiT, nullptr, nullptr, nullptr,
            nullptr, nullptr, msgA, baseB, M);
        // 3 iters: msg' = relu(g6(msg)@Wh1 + base)
        mfma_gemm<1, true, false, false><<<gG, 512, 0, stream>>>(
            msgA, a2a, Wh1T, nullptr, nullptr, nullptr, nullptr, nullptr,
            baseB, nullptr, msgB, nullptr, M);
        mfma_gemm<1, true, false, false><<<gG, 512, 0, stream>>>(
            msgB, a2a, Wh1T, nullptr, nullptr, nullptr, nullptr, nullptr,
            baseB, nullptr, msgA, nullptr, M);
        mfma_gemm<1, true, false, false><<<gG, 512, 0, stream>>>(
            msgA, a2a, Wh1T, nullptr, nullptr, nullptr, nullptr, nullptr,
            baseB, nullptr, msgB, nullptr, M);
    } else {
        mfma_gemm<0, false, true, false><<<gG, 512, 0, stream>>>(
            nullptr, nullptr, nullptr, atomf, WiT, nullptr, nullptr, nullptr,
            nullptr, nullptr, msgA, nullptr, M);
        mfma_gemm<0, true, true, true><<<gG, 512, 0, stream>>>(
            msgA, a2a, Wh1T, atomf, WiT, f_bonds, a2b, Wh2T,
            nullptr, nullptr, msgB, nullptr, M);
        mfma_gemm<0, true, true, true><<<gG, 512, 0, stream>>>(
            msgB, a2a, Wh1T, atomf, WiT, f_bonds, a2b, Wh2T,
            nullptr, nullptr, msgA, nullptr, M);
        mfma_gemm<0, true, true, true><<<gG, 512, 0, stream>>>(
            msgA, a2a, Wh1T, atomf, WiT, f_bonds, a2b, Wh2T,
            nullptr, nullptr, msgB, nullptr, M);
    }
    // hid = relu(g6(msgB)@Wo2 + atomf@Wo1 + b_o) -> msgA
    mfma_gemm<2, true, true, false><<<gG, 512, 0, stream>>>(
        msgB, a2a, Wo2T, atomf, Wo1T, nullptr, nullptr, nullptr,
        nullptr, b_o, msgA, nullptr, M);
    // segment mean + counts
    seg_k<<<NM, 512, 0, stream>>>(msgA, flags, mol_ids, out, M, NM);
}

// Round 6
// 1548.633 us; speedup vs baseline: 1.3518x; 1.3518x over previous
//
#include <hip/hip_runtime.h>
#include <hip/hip_bf16.h>
#include <cstddef>

#define HIDDEN 512
#define ATOM_FDIM 133
#define BOND_FDIM 14
#define FB_DIM 147
#define MAX_NB 6
#define BM 64
#define NT_MSG 16          // K-tiles message phase (512/32)
#define NT_ATOM 5          // K-tiles atom phase (160/32, pad of 133)

typedef __attribute__((ext_vector_type(8))) short s16x8;
typedef __attribute__((ext_vector_type(4))) float f32x4;

__device__ __forceinline__ float uf(unsigned short u) {
    return __uint_as_float(((unsigned)u) << 16);
}
__device__ __forceinline__ unsigned short fb(float f) {
    __hip_bfloat16 h = __float2bfloat16(f);
    return *reinterpret_cast<unsigned short*>(&h);
}

// LDS A tile: 64 chunks(16B each, = k-octet) x 64 rows, XOR-swizzled so the
// staging ds_write (same-row threads at 1024B stride) spreads across banks.
#define A_UNIT(ch, row) (((ch) << 6) + ((row) ^ ((ch) & 7)))

// ---------------------------------------------------------------------------
// One-time weight convert: f32 [Ksrc][512] -> bf16 MFMA-fragment order.
// Chunk c: tile=c>>11, n=(c&2047)>>2, s=c&3 holds W[tile*32+s*8+e][n].
// A wave's 8 fragment loads each cover a contiguous 1 KB region -> coalesced.
// ---------------------------------------------------------------------------
__global__ __launch_bounds__(256) void cvt_w(const float* __restrict__ src,
                                             unsigned short* __restrict__ dst,
                                             int Ksrc, int nchunks)
{
    int c = blockIdx.x * 256 + threadIdx.x;
    if (c >= nchunks) return;
    int tile = c >> 11, pc = c & 2047, n = pc >> 2, s = pc & 3;
    s16x8 o;
    #pragma unroll
    for (int e = 0; e < 8; e++) {
        int k = tile * 32 + s * 8 + e;
        float v = (k < Ksrc) ? src[(size_t)k * HIDDEN + n] : 0.f;
        o[e] = (short)fb(v);
    }
    reinterpret_cast<s16x8*>(dst)[c] = o;
}

// ---------------------------------------------------------------------------
// MFMA multi-phase GEMM. 512 thr = 8 waves (2M x 4N), BM=64 x BN=512.
// A (gather-sum) staged ONCE into 64 KB LDS (1 barrier), then a barrier-free
// K-loop: per tile {2 LDS A-frags + 8 coalesced global B-frags (1-ahead
// reg-prefetch) + 16 MFMAs}.  B tiles are L2-hot fragment-ordered weights.
// ---------------------------------------------------------------------------
template<int EPI, bool P0, bool P1, bool P2>
__global__ __launch_bounds__(512, 4) void mfma_gemm(
    const unsigned short* __restrict__ msg, const int* __restrict__ a2a,
    const unsigned short* __restrict__ Wm,
    const float* __restrict__ atomf, const unsigned short* __restrict__ Wa,
    const float* __restrict__ fbonds, const int* __restrict__ a2b,
    const unsigned short* __restrict__ Wb,
    const unsigned short* __restrict__ base, const float* __restrict__ bias,
    unsigned short* __restrict__ outv, unsigned short* __restrict__ baseOut,
    int M)
{
    __shared__ s16x8 As[64 * 64];                    // 64 KB

    const int t    = threadIdx.x;
    const int m0   = blockIdx.x * BM;
    const int lane = t & 63;
    const int l15  = lane & 15, lhi = lane >> 4;
    const int w    = t >> 6, wm = w >> 2, wn = w & 3;
    const int rs   = t >> 3, oc = t & 7;             // staging: row, octet

    int srow = m0 + rs; if (srow >= M) srow = M - 1;

    f32x4 acc[2][8];
    #pragma unroll
    for (int mr = 0; mr < 2; mr++)
        #pragma unroll
        for (int nr = 0; nr < 8; nr++)
            acc[mr][nr] = (f32x4){0.f, 0.f, 0.f, 0.f};

#define LOADB(B_, WT, TILE) do {                                              \
    const s16x8* bb_ = reinterpret_cast<const s16x8*>(                        \
        (WT) + (size_t)(TILE) * (HIDDEN * 32)) + ((wn * 128 + l15) * 4 + lhi);\
    _Pragma("unroll")                                                         \
    for (int nr_ = 0; nr_ < 8; nr_++) B_[nr_] = bb_[nr_ * 64];                \
} while (0)

#define TILE_MFMA(TILE, B_) do {                                              \
    s16x8 a0_ = As[A_UNIT((TILE) * 4 + lhi, wm * 32 + l15)];                  \
    s16x8 a1_ = As[A_UNIT((TILE) * 4 + lhi, wm * 32 + 16 + l15)];             \
    _Pragma("unroll")                                                         \
    for (int nr_ = 0; nr_ < 8; nr_++) {                                       \
        acc[0][nr_] = __builtin_amdgcn_mfma_f32_16x16x32_bf16(a0_, B_[nr_], acc[0][nr_], 0, 0, 0); \
        acc[1][nr_] = __builtin_amdgcn_mfma_f32_16x16x32_bf16(a1_, B_[nr_], acc[1][nr_], 0, 0, 0); \
    }                                                                         \
} while (0)

#define PHASE(WT, NT) do {                                                    \
    s16x8 b0_[8], b1_[8];                                                     \
    LOADB(b0_, WT, 0);                                                        \
    _Pragma("unroll")                                                         \
    for (int tp_ = 0; tp_ < (NT) / 2; ++tp_) {                                \
        LOADB(b1_, WT, 2 * tp_ + 1);                                          \
        TILE_MFMA(2 * tp_, b0_);                                              \
        if (2 * tp_ + 2 < (NT)) LOADB(b0_, WT, 2 * tp_ + 2);                  \
        TILE_MFMA(2 * tp_ + 1, b1_);                                          \
    }                                                                         \
    if ((NT) & 1) TILE_MFMA((NT) - 1, b0_);                                   \
} while (0)

    // ---- P0: gathered message, K = 512, one-shot staged ----
    if (P0) {
        const unsigned short* pA[MAX_NB];
        #pragma unroll
        for (int j = 0; j < MAX_NB; j++)
            pA[j] = msg + (size_t)a2a[(size_t)srow * MAX_NB + j] * HIDDEN;

        s16x8 v0[MAX_NB], v1[MAX_NB];
        #pragma unroll
        for (int j = 0; j < MAX_NB; j++)
            v0[j] = *reinterpret_cast<const s16x8*>(pA[j] + oc * 8);
        #pragma unroll
        for (int c8 = 0; c8 < 8; ++c8) {
            int ch = c8 * 8 + oc;
            if (c8 & 1) {
                if (c8 < 7) {
                    #pragma unroll
                    for (int j = 0; j < MAX_NB; j++)
                        v0[j] = *reinterpret_cast<const s16x8*>(pA[j] + (ch + 8) * 8);
                }
                float s[8] = {0.f,0.f,0.f,0.f,0.f,0.f,0.f,0.f};
                #pragma unroll
                for (int j = 0; j < MAX_NB; j++)
                    #pragma unroll
                    for (int e = 0; e < 8; e++) s[e] += uf((unsigned short)v1[j][e]);
                s16x8 o;
                #pragma unroll
                for (int e = 0; e < 8; e++) o[e] = (short)fb(s[e]);
                As[A_UNIT(ch, rs)] = o;
            } else {
                if (c8 < 7) {
                    #pragma unroll
                    for (int j = 0; j < MAX_NB; j++)
                        v1[j] = *reinterpret_cast<const s16x8*>(pA[j] + (ch + 8) * 8);
                }
                float s[8] = {0.f,0.f,0.f,0.f,0.f,0.f,0.f,0.f};
                #pragma unroll
                for (int j = 0; j < MAX_NB; j++)
                    #pragma unroll
                    for (int e = 0; e < 8; e++) s[e] += uf((unsigned short)v0[j][e]);
                s16x8 o;
                #pragma unroll
                for (int e = 0; e < 8; e++) o[e] = (short)fb(s[e]);
                As[A_UNIT(ch, rs)] = o;
            }
        }
        __syncthreads();
        PHASE(Wm, NT_MSG);
    }

    // ---- P1: direct atom features, K = 160 (pad of 133) ----
    if (P1) {
        if (P0) __syncthreads();
        {
            int grow = m0 + rs;
            bool ok = grow < M;
            #pragma unroll
            for (int c8 = 0; c8 < 3; ++c8) {
                int ch = c8 * 8 + oc;
                s16x8 o;
                #pragma unroll
                for (int e = 0; e < 8; e++) {
                    int k = ch * 8 + e;
                    float v = (ok && k < ATOM_FDIM)
                                  ? atomf[(size_t)grow * ATOM_FDIM + k] : 0.f;
                    o[e] = (short)fb(v);
                }
                As[A_UNIT(ch, rs)] = o;
            }
        }
        __syncthreads();
        PHASE(Wa, NT_ATOM);
    }

    // ---- P2: gathered bond features, K = 32 (pad of 14) ----
    if (P2) {
        __syncthreads();
        if (oc < 4) {
            int ch = oc;
            float s[8] = {0.f,0.f,0.f,0.f,0.f,0.f,0.f,0.f};
            #pragma unroll
            for (int j = 0; j < MAX_NB; j++) {
                int b = a2b[(size_t)srow * MAX_NB + j];
                #pragma unroll
                for (int e = 0; e < 8; e++) {
                    int k = ch * 8 + e;
                    if (k < BOND_FDIM) s[e] += fbonds[(size_t)b * FB_DIM + ATOM_FDIM + k];
                }
            }
            s16x8 o;
            #pragma unroll
            for (int e = 0; e < 8; e++) o[e] = (short)fb(s[e]);
            As[A_UNIT(ch, rs)] = o;
        }
        __syncthreads();
        PHASE(Wb, 1);
    }

    // ---- epilogue ----
    #pragma unroll
    for (int mr = 0; mr < 2; mr++) {
        #pragma unroll
        for (int nr = 0; nr < 8; nr++) {
            int col = wn * 128 + nr * 16 + l15;
            #pragma unroll
            for (int rg = 0; rg < 4; rg++) {
                int row = m0 + wm * 32 + mr * 16 + lhi * 4 + rg;
                if (row >= M) continue;
                size_t idx = (size_t)row * HIDDEN + col;
                float v = acc[mr][nr][rg];
                if (EPI == 0) {
                    outv[idx] = fb(fmaxf(v, 0.f));
                    if (baseOut) baseOut[idx] = fb(v + uf(baseOut[idx]));
                } else if (EPI == 1) {
                    outv[idx] = fb(fmaxf(v + uf(base[idx]), 0.f));
                } else {
                    outv[idx] = fb(fmaxf(v + bias[col], 0.f));
                }
            }
        }
    }
#undef PHASE
#undef TILE_MFMA
#undef LOADB
}

// ---------------------------------------------------------------------------
// flags[i] = (sum of atom_features row i) > 0.  One wave per row.
// ---------------------------------------------------------------------------
__global__ __launch_bounds__(256) void flags_k(const float* __restrict__ af,
                                               float* __restrict__ flags, int M)
{
    int w    = (blockIdx.x * 256 + threadIdx.x) >> 6;
    int lane = threadIdx.x & 63;
    if (w >= M) return;
    const float* row = af + (size_t)w * ATOM_FDIM;
    float s = 0.f;
    for (int c = lane; c < ATOM_FDIM; c += 64) s += row[c];
    #pragma unroll
    for (int off = 32; off; off >>= 1) s += __shfl_down(s, off);
    if (lane == 0) flags[w] = (s > 0.f) ? 1.f : 0.f;
}

// ---------------------------------------------------------------------------
// c_b[i] = (sum_j f_bonds[a2b[i][j]][133:147]) @ W_h[512:526] -> bf16
// ---------------------------------------------------------------------------
__global__ __launch_bounds__(256) void cb_k(const float* __restrict__ f_bonds,
                                            const int*   __restrict__ a2b,
                                            const float* __restrict__ Wh2,
                                            unsigned short* __restrict__ cb, int M)
{
    int atom = blockIdx.x * 4 + (threadIdx.x >> 6);
    int lane = threadIdx.x & 63;
    if (atom >= M) return;
    int bidx = (lane < MAX_NB) ? a2b[(size_t)atom * MAX_NB + lane] : 0;
    float nb = 0.f;
    if (lane < BOND_FDIM) {
        #pragma unroll
        for (int j = 0; j < MAX_NB; j++) {
            int b = __shfl(bidx, j);
            nb += f_bonds[(size_t)b * FB_DIM + ATOM_FDIM + lane];
        }
    }
    float acc[8];
    #pragma unroll
    for (int ci = 0; ci < 8; ci++) acc[ci] = 0.f;
    #pragma unroll
    for (int k = 0; k < BOND_FDIM; k++) {
        float nbk = __shfl(nb, k);
        #pragma unroll
        for (int ci = 0; ci < 8; ci++)
            acc[ci] += nbk * Wh2[(size_t)k * HIDDEN + lane + (ci << 6)];
    }
    size_t rb = (size_t)atom * HIDDEN;
    #pragma unroll
    for (int ci = 0; ci < 8; ci++) cb[rb + lane + (ci << 6)] = fb(acc[ci]);
}

// ---------------------------------------------------------------------------
// Per-molecule segment mean + counts; mol_ids sorted -> binary search bounds.
// ---------------------------------------------------------------------------
__global__ __launch_bounds__(512) void seg_k(const unsigned short* __restrict__ hid,
                                             const float* __restrict__ flags,
                                             const int*   __restrict__ mol_ids,
                                             float* __restrict__ out, int M, int NM)
{
    int m = blockIdx.x;
    int t = threadIdx.x;
    int lo = 0, hi = M;
    while (lo < hi) { int mid = (lo + hi) >> 1; if (mol_ids[mid] < m) lo = mid + 1; else hi = mid; }
    int s = lo;
    lo = 0; hi = M;
    while (lo < hi) { int mid = (lo + hi) >> 1; if (mol_ids[mid] < m + 1) lo = mid + 1; else hi = mid; }
    int e = lo;

    float acc = 0.f;
    for (int a = s; a < e; a++) acc += uf(hid[(size_t)a * HIDDEN + t]);
    float nzp = 0.f;
    for (int a = s + t; a < e; a += 512) nzp += flags[a];
    __shared__ float red[512];
    red[t] = nzp; __syncthreads();
    for (int off = 256; off; off >>= 1) { if (t < off) red[t] += red[t + off]; __syncthreads(); }

    int cnt = e - s;
    float inv = 1.f / fmaxf((float)cnt, 1.f);
    out[(size_t)m * HIDDEN + t] = acc * inv;
    if (t == 0) {
        out[(size_t)NM * HIDDEN + 2 * m]     = red[0];
        out[(size_t)NM * HIDDEN + 2 * m + 1] = (float)cnt;
    }
}

// ---------------------------------------------------------------------------
extern "C" void kernel_launch(void* const* d_in, const int* in_sizes, int n_in,
                              void* d_out, int out_size, void* d_ws, size_t ws_size,
                              hipStream_t stream)
{
    const float* atomf   = (const float*)d_in[0];
    const float* f_bonds = (const float*)d_in[1];
    const int*   a2a     = (const int*)d_in[2];
    const int*   a2b     = (const int*)d_in[3];
    const int*   mol_ids = (const int*)d_in[4];
    const float* W_i     = (const float*)d_in[5];
    const float* W_h     = (const float*)d_in[6];
    const float* W_o     = (const float*)d_in[7];
    const float* b_o     = (const float*)d_in[8];
    float* out = (float*)d_out;

    const int M  = in_sizes[2] / MAX_NB;   // 100000
    const int NM = 1000;
    const size_t SZ  = (size_t)M * HIDDEN;
    const size_t SZb = SZ * sizeof(unsigned short);

    const float* Wh2f = W_h + (size_t)HIDDEN * HIDDEN;

    // ---- workspace layout ----
    const size_t TCH = HIDDEN * 32;             // ushorts per tile (16384)
    unsigned short* WiT  = (unsigned short*)d_ws;
    unsigned short* Wh1T = WiT  + 5  * TCH;
    unsigned short* Wh2T = Wh1T + 16 * TCH;
    unsigned short* Wo1T = Wh2T + 1  * TCH;
    unsigned short* Wo2T = Wo1T + 5  * TCH;
    unsigned short* wend = Wo2T + 16 * TCH;     // 43 tiles total
    float* flags = (float*)wend;
    char* p = (char*)(flags + M);
    const size_t fixed = (size_t)((char*)p - (char*)d_ws);

    const bool path3 = (ws_size >= fixed + 3 * SZb);
    unsigned short* baseB = nullptr;
    unsigned short *msgA, *msgB;
    if (path3) {
        baseB = (unsigned short*)p; p += SZb;
        msgA  = (unsigned short*)p; p += SZb;
        msgB  = (unsigned short*)p;
    } else {
        msgA  = (unsigned short*)p; p += SZb;
        msgB  = (unsigned short*)p;
    }

    const int gA = (M + 3) / 4;
    const int gG = (M + BM - 1) / BM;

    // ---- weight conversion (fragment-ordered bf16 tiles) ----
    cvt_w<<<(5  * 2048 + 255) / 256, 256, 0, stream>>>(W_i,  WiT,  ATOM_FDIM, 5  * 2048);
    cvt_w<<<(16 * 2048 + 255) / 256, 256, 0, stream>>>(W_h,  Wh1T, HIDDEN,    16 * 2048);
    cvt_w<<<(1  * 2048 + 255) / 256, 256, 0, stream>>>(Wh2f, Wh2T, BOND_FDIM, 1  * 2048);
    cvt_w<<<(5  * 2048 + 255) / 256, 256, 0, stream>>>(W_o,  Wo1T, ATOM_FDIM, 5  * 2048);
    cvt_w<<<(16 * 2048 + 255) / 256, 256, 0, stream>>>(W_o + (size_t)ATOM_FDIM * HIDDEN,
                                                       Wo2T, HIDDEN, 16 * 2048);
    flags_k<<<gA, 256, 0, stream>>>(atomf, flags, M);

    if (path3) {
        cb_k<<<gA, 256, 0, stream>>>(f_bonds, a2b, Wh2f, baseB, M);
        // msgA = relu(inp); baseB += inp
        mfma_gemm<0, false, true, false><<<gG, 512, 0, stream>>>(
            nullptr, nullptr, nullptr, atomf, WiT, nullptr, nullptr, nullptr,
            nullptr, nullptr, msgA, baseB, M);
        // 3 iters: msg' = relu(g6(msg)@Wh1 + base)
        mfma_gemm<1, true, false, false><<<gG, 512, 0, stream>>>(
            msgA, a2a, Wh1T, nullptr, nullptr, nullptr, nullptr, nullptr,
            baseB, nullptr, msgB, nullptr, M);
        mfma_gemm<1, true, false, false><<<gG, 512, 0, stream>>>(
            msgB, a2a, Wh1T, nullptr, nullptr, nullptr, nullptr, nullptr,
            baseB, nullptr, msgA, nullptr, M);
        mfma_gemm<1, true, false, false><<<gG, 512, 0, stream>>>(
            msgA, a2a, Wh1T, nullptr, nullptr, nullptr, nullptr, nullptr,
            baseB, nullptr, msgB, nullptr, M);
    } else {
        mfma_gemm<0, false, true, false><<<gG, 512, 0, stream>>>(
            nullptr, nullptr, nullptr, atomf, WiT, nullptr, nullptr, nullptr,
            nullptr, nullptr, msgA, nullptr, M);
        mfma_gemm<0, true, true, true><<<gG, 512, 0, stream>>>(
            msgA, a2a, Wh1T, atomf, WiT, f_bonds, a2b, Wh2T,
            nullptr, nullptr, msgB, nullptr, M);
        mfma_gemm<0, true, true, true><<<gG, 512, 0, stream>>>(
            msgB, a2a, Wh1T, atomf, WiT, f_bonds, a2b, Wh2T,
            nullptr, nullptr, msgA, nullptr, M);
        mfma_gemm<0, true, true, true><<<gG, 512, 0, stream>>>(
            msgA, a2a, Wh1T, atomf, WiT, f_bonds, a2b, Wh2T,
            nullptr, nullptr, msgB, nullptr, M);
    }
    // hid = relu(g6(msgB)@Wo2 + atomf@Wo1 + b_o) -> msgA
    mfma_gemm<2, true, true, false><<<gG, 512, 0, stream>>>(
        msgB, a2a, Wo2T, atomf, Wo1T, nullptr, nullptr, nullptr,
        nullptr, b_o, msgA, nullptr, M);
    // segment mean + counts
    seg_k<<<NM, 512, 0, stream>>>(msgA, flags, mol_ids, out, M, NM);
}